// Round 7
// baseline (252.552 us; speedup 1.0000x reference)
//
#include <hip/hip_runtime.h>
#include <hip/hip_bf16.h>
#include <stdint.h>

typedef __attribute__((ext_vector_type(8))) short bf8;   // 8 bf16 (4 VGPR)
typedef __attribute__((ext_vector_type(4))) short bf4;
typedef __attribute__((ext_vector_type(2))) short bf2;
typedef __attribute__((ext_vector_type(4))) float f32x4;

__device__ inline short f2bf(float f) {
  union { __hip_bfloat16 h; short s; } u;
  u.h = __float2bfloat16(f);
  return u.s;
}
__device__ inline float bf2f(short s) {
  union { short s; __hip_bfloat16 h; } u;
  u.s = s;
  return __bfloat162float(u.h);
}

__device__ inline f32x4 mfma16(bf8 a, bf8 b, f32x4 c) {
  return __builtin_amdgcn_mfma_f32_16x16x32_bf16(a, b, c, 0, 0, 0);
}

// ---------------------------------------------------------------- mega kernel 1
// 1728 blocks:
//  bid <1024 : kv1 gemm (64m x 16n), K=256, bf16 out + bias
//  bid <1280 : qproj (16m x 8n x 2 kchunks) -> f32 partials (+x->cat copy);
//              last-arriver fixup: qb = bf16((p0+p1+bq)*0.125*log2e)
//  bid <1536 : kv2 (4m x 16n x 4 kchunks) -> f32 partials;
//              last-arriver fixup: kv2 = bf16(sum4+bkv2)
//  else      : wT[512][1536] = transpose(wproj) bf16 (192 blocks)
// Counter layout: cnt[0..127] qproj tiles, cnt[128..191] kv2 tiles.
__global__ __launch_bounds__(256) void mega1_k(
    const float* __restrict__ x, const float* __restrict__ fore,
    const float* __restrict__ post,
    const float* __restrict__ wq, const float* __restrict__ bq,
    const float* __restrict__ wkv1, const float* __restrict__ bkv1,
    const float* __restrict__ wkv2, const float* __restrict__ bkv2,
    const float* __restrict__ wproj,
    short* __restrict__ kv1, short* __restrict__ cat,
    float* __restrict__ qpart, float* __restrict__ kv2part,
    short* __restrict__ qb, short* __restrict__ kv2, short* __restrict__ wT,
    int* __restrict__ cnt)
{
  __shared__ __align__(16) short a_lds[2][128 * 40];
  __shared__ __align__(16) short b_lds[2][64 * 40];
  __shared__ int s_old;
  const int bid = blockIdx.x, tid = threadIdx.x;

  if (bid >= 1536) {                     // ---- wproj transpose
    float (*tl)[65] = reinterpret_cast<float(*)[65]>(&a_lds[0][0]);
    int tb = bid - 1536;                 // 0..191
    int kt = tb % 24, nt = tb / 24;
    int k0 = kt * 64, n0 = nt * 64;
    int kr = tid >> 2, c4 = tid & 3;
#pragma unroll
    for (int i = 0; i < 4; ++i) {
      int cc = c4 + i * 4;
      float4 v = *(const float4*)&wproj[(size_t)(k0 + kr) * 512 + n0 + cc * 4];
      tl[kr][cc * 4 + 0] = v.x; tl[kr][cc * 4 + 1] = v.y;
      tl[kr][cc * 4 + 2] = v.z; tl[kr][cc * 4 + 3] = v.w;
    }
    __syncthreads();
    int nr = tid >> 2, p = tid & 3;
#pragma unroll
    for (int i = 0; i < 2; ++i) {
      int kk = p * 16 + i * 8;
      bf8 o;
#pragma unroll
      for (int j = 0; j < 8; ++j) o[j] = f2bf(tl[kk + j][nr]);
      *(bf8*)&wT[(size_t)(n0 + nr) * 1536 + k0 + kk] = o;
    }
    return;
  }

  const float *A, *W, *bias = nullptr;
  short* out = nullptr;
  float* outf = nullptr;
  int N, lda, ldo, m0, n0, koff, tile = -1, nchunk = 0;
  bool wcat = false;
  if (bid < 1024) {          // kv1
    A = fore; W = wkv1; bias = bkv1; out = kv1;
    N = 1024; lda = 256; ldo = 1024; koff = 0;
    m0 = (bid >> 4) * 128; n0 = (bid & 15) * 64;
  } else if (bid < 1280) {   // qproj
    int j = bid - 1024; int kc = j >> 7; j &= 127;
    A = x; W = wq; outf = qpart + (size_t)kc * (2048 * 512);
    N = 512; lda = 512; ldo = 512; koff = kc * 256;
    m0 = (j >> 3) * 128; n0 = (j & 7) * 64;
    wcat = (j & 7) == 0; tile = j; nchunk = 2;
  } else {                   // kv2
    int j = bid - 1280; int kc = j >> 6; j &= 63;
    A = post; W = wkv2; outf = kv2part + (size_t)kc * (512 * 1024);
    N = 1024; lda = 1024; ldo = 1024; koff = kc * 256;
    m0 = (j >> 4) * 128; n0 = (j & 15) * 64;
    tile = 128 + j; nchunk = 4;
  }

  const int w = tid >> 6, lane = tid & 63, g = lane >> 4, lr = lane & 15;
  const int wrow = w & 1, wcol = w >> 1;

  f32x4 z = {0.f, 0.f, 0.f, 0.f};
  f32x4 acc[4][2];
#pragma unroll
  for (int mi = 0; mi < 4; ++mi)
#pragma unroll
    for (int ni = 0; ni < 2; ++ni) acc[mi][ni] = z;

  const int arow = tid >> 3, ac4 = tid & 7;
  const int bcol = tid & 63, bj4 = tid >> 6;

  float4 ra[4], rna[4];
  float rw[8], rnw[8];

  auto LOADA = [&](int kg, float4* af, float* wg) {
#pragma unroll
    for (int i = 0; i < 4; ++i)
      af[i] = *(const float4*)&A[(size_t)(m0 + arow + 32 * i) * lda + kg + ac4 * 4];
#pragma unroll
    for (int j = 0; j < 8; ++j)
      wg[j] = W[(size_t)(kg + bj4 * 8 + j) * N + n0 + bcol];
  };
  auto STAGE = [&](int b, const float4* af, const float* wg, int kg) {
#pragma unroll
    for (int i = 0; i < 4; ++i) {
      int rr = arow + 32 * i;
      int s = (ac4 >> 1) ^ (rr & 3);
      bf4 o;
      o[0] = f2bf(af[i].x); o[1] = f2bf(af[i].y);
      o[2] = f2bf(af[i].z); o[3] = f2bf(af[i].w);
      *(bf4*)&a_lds[b][rr * 40 + s * 8 + (ac4 & 1) * 4] = o;
      if (wcat)
        *(bf4*)&cat[(size_t)(m0 + rr) * 1536 + kg + ac4 * 4] = o;
    }
    int s = bj4 ^ (bcol & 3);
    bf8 o;
#pragma unroll
    for (int j = 0; j < 8; ++j) o[j] = f2bf(wg[j]);
    *(bf8*)&b_lds[b][bcol * 40 + s * 8] = o;
  };

  LOADA(koff, ra, rw);
  STAGE(0, ra, rw, koff);
  LOADA(koff + 32, rna, rnw);
  __syncthreads();

#pragma unroll
  for (int it = 0; it < 8; ++it) {
    if (it < 7) STAGE((it + 1) & 1, rna, rnw, koff + (it + 1) * 32);
    if (it < 6) LOADA(koff + (it + 2) * 32, rna, rnw);

    const int b = it & 1;
    bf8 afr[4], bfr[2];
#pragma unroll
    for (int mi = 0; mi < 4; ++mi) {
      int row = wrow * 64 + mi * 16 + lr;
      afr[mi] = *(const bf8*)&a_lds[b][row * 40 + ((g ^ (row & 3)) << 3)];
    }
#pragma unroll
    for (int ni = 0; ni < 2; ++ni) {
      int col = wcol * 32 + ni * 16 + lr;
      bfr[ni] = *(const bf8*)&b_lds[b][col * 40 + ((g ^ (col & 3)) << 3)];
    }
#pragma unroll
    for (int mi = 0; mi < 4; ++mi)
#pragma unroll
      for (int ni = 0; ni < 2; ++ni)
        acc[mi][ni] = mfma16(afr[mi], bfr[ni], acc[mi][ni]);
    __syncthreads();
  }

#pragma unroll
  for (int ni = 0; ni < 2; ++ni) {
    int col = n0 + wcol * 32 + ni * 16 + lr;
    float bv = (tile < 0) ? bias[col] : 0.f;
#pragma unroll
    for (int mi = 0; mi < 4; ++mi) {
      int rowb = m0 + wrow * 64 + mi * 16 + g * 4;
#pragma unroll
      for (int r = 0; r < 4; ++r) {
        float val = acc[mi][ni][r] + bv;
        if (tile < 0)
          out[(size_t)(rowb + r) * ldo + col] = f2bf(val);
        else
          outf[(size_t)(rowb + r) * ldo + col] = val;
      }
    }
  }

  if (tile < 0) return;

  // ---- split-K fixup: last arriver reduces partials
  __syncthreads();
  if (tid == 0) { __threadfence(); s_old = atomicAdd(&cnt[tile], 1); }
  __syncthreads();
  if (s_old != nchunk - 1) return;
  __threadfence();

  const int c4 = (tid & 15) * 4, r0 = tid >> 4;
  if (nchunk == 2) {
    const float qsc = 0.125f * 1.44269504088896f;
#pragma unroll
    for (int pass = 0; pass < 8; ++pass) {
      int row = m0 + r0 + pass * 16;
      float4 a = *(const float4*)&qpart[(size_t)row * 512 + n0 + c4];
      float4 b = *(const float4*)&qpart[1048576 + (size_t)row * 512 + n0 + c4];
      float4 bv = *(const float4*)&bq[n0 + c4];
      bf4 o;
      o[0] = f2bf((a.x + b.x + bv.x) * qsc);
      o[1] = f2bf((a.y + b.y + bv.y) * qsc);
      o[2] = f2bf((a.z + b.z + bv.z) * qsc);
      o[3] = f2bf((a.w + b.w + bv.w) * qsc);
      *(bf4*)&qb[(size_t)row * 512 + n0 + c4] = o;
    }
  } else {
#pragma unroll
    for (int pass = 0; pass < 8; ++pass) {
      int row = m0 + r0 + pass * 16;
      float4 a = *(const float4*)&kv2part[(size_t)row * 1024 + n0 + c4];
      float4 b = *(const float4*)&kv2part[524288 + (size_t)row * 1024 + n0 + c4];
      float4 c = *(const float4*)&kv2part[1048576 + (size_t)row * 1024 + n0 + c4];
      float4 d = *(const float4*)&kv2part[1572864 + (size_t)row * 1024 + n0 + c4];
      float4 bv = *(const float4*)&bkv2[n0 + c4];
      bf4 o;
      o[0] = f2bf(a.x + b.x + c.x + d.x + bv.x);
      o[1] = f2bf(a.y + b.y + c.y + d.y + bv.y);
      o[2] = f2bf(a.z + b.z + c.z + d.z + bv.z);
      o[3] = f2bf(a.w + b.w + c.w + d.w + bv.w);
      *(bf4*)&kv2[(size_t)row * 1024 + n0 + c4] = o;
    }
  }
}

// ---------------------------------------------------------------- attention (merged, split-K, fused combine)
// bid<1024: attn1 (chunk 512, ns 8); else attn2 (chunk 64, ns 4).
// Decode keeps all splits of a (qt,h,bb) group AND all kv-chunk sharers on one XCD
// (bids differ by multiples of 8). Last split block combines+normalizes into cat.
// cnt layout: cnt[192..319] region1 groups, cnt[320..447] region2 groups.
__global__ __launch_bounds__(256) void attn_k(
    const short* __restrict__ q,
    const short* __restrict__ kv1, const short* __restrict__ kv2,
    short* __restrict__ o1, float* __restrict__ l1,
    short* __restrict__ o2, float* __restrict__ l2,
    short* __restrict__ cat, int* __restrict__ cnt)
{
  __shared__ __align__(16) short k_lds[64 * 64];   // [lc][d] XOR-swizzled octets
  __shared__ __align__(16) short v_lds[64 * 72];   // [d][lc-permuted]
  __shared__ int s_old;
  const int tid = threadIdx.x;
  const int w = tid >> 6, lane = tid & 63, g = lane >> 4, lr = lane & 15;

  const int bid = blockIdx.x;
  const short* kvsrc;
  short* opart;
  float* lpart;
  int qt, h, bb, split, chunk, Lc, nsplit, ocol, gidc;
  if (bid < 1024) {
    qt = bid >> 7; int j = bid & 127;
    h = j & 7; int zz = j >> 3;
    bb = zz >> 3; split = zz & 7;
    kvsrc = kv1; opart = o1; lpart = l1; chunk = 512; Lc = 4096;
    nsplit = 8; ocol = 512;
    gidc = 192 + (bb * 8 + h) * 8 + qt;
  } else {
    int j2 = bid - 1024;
    qt = j2 >> 6; int r = j2 & 63;
    h = r & 7; int zz = r >> 3;
    bb = zz >> 2; split = zz & 3;
    kvsrc = kv2; opart = o2; lpart = l2; chunk = 64; Lc = 256;
    nsplit = 4; ocol = 1024;
    gidc = 320 + (bb * 8 + h) * 8 + qt;
  }

  // Q: 32 rows per wave, 2 sets of 16 (B-operand fragments)
  const int qbase = bb * 1024 + qt * 128 + w * 32;
  bf8 qfA[2], qfB[2];
#pragma unroll
  for (int s2 = 0; s2 < 2; ++s2) {
    const short* qp = &q[(size_t)(qbase + s2 * 16 + lr) * 512 + h * 64];
    qfA[s2] = *(const bf8*)&qp[g * 8];
    qfB[s2] = *(const bf8*)&qp[32 + g * 8];
  }

  const f32x4 z = {0.f, 0.f, 0.f, 0.f};
  f32x4 oaccT[2][4];   // [set][dt] : O^T rows d=16dt+4g+r, col q=lr
#pragma unroll
  for (int s2 = 0; s2 < 2; ++s2)
#pragma unroll
    for (int i = 0; i < 4; ++i) oaccT[s2][i] = z;
  float lsum_l[2] = {0.f, 0.f};

  const short* kvb = kvsrc + (size_t)bb * Lc * 1024 + (size_t)split * chunk * 1024;

  const int krow = tid >> 2, ksl = tid & 3;
  const short* kgp = kvb + (size_t)krow * 1024 + h * 64;
  const int vi = tid & 31, vj = tid >> 5;
  const short* vgp = kvb + (size_t)(2 * vi) * 1024 + 512 + h * 64 + vj * 8;
  const int lc0 = 2 * vi;
  const int vpos = (lc0 & 32) + ((lc0 & 12) << 1) + ((lc0 & 16) >> 2) + (lc0 & 3);

  bf8 k0c, k1c, v0c, v1c;
  k0c = *(const bf8*)(kgp + ksl * 8);
  k1c = *(const bf8*)(kgp + (ksl + 4) * 8);
  v0c = *(const bf8*)vgp;
  v1c = *(const bf8*)(vgp + 1024);

  const int nit = chunk >> 6;
  for (int it = 0; it < nit; ++it) {
    __syncthreads();
    *(bf8*)&k_lds[krow * 64 + ((ksl ^ (krow & 7)) << 3)] = k0c;
    *(bf8*)&k_lds[krow * 64 + (((ksl + 4) ^ (krow & 7)) << 3)] = k1c;
#pragma unroll
    for (int jj = 0; jj < 8; ++jj) {
      int d = vj * 8 + jj;
      bf2 pr; pr[0] = v0c[jj]; pr[1] = v1c[jj];
      *(bf2*)&v_lds[d * 72 + vpos] = pr;
    }
    __syncthreads();
    if (it + 1 < nit) {
      size_t off = (size_t)64 * 1024 * (it + 1);
      k0c = *(const bf8*)(kgp + off + ksl * 8);
      k1c = *(const bf8*)(kgp + off + (ksl + 4) * 8);
      v0c = *(const bf8*)(vgp + off);
      v1c = *(const bf8*)(vgp + off + 1024);
    }

    // S^T = (K Q^T) ; q prescaled by 0.125*log2e so p = exp2(s')
    f32x4 sv[2][4];
#pragma unroll
    for (int t = 0; t < 4; ++t) {
      int lc = t * 16 + lr;
      bf8 kf0 = *(const bf8*)&k_lds[lc * 64 + ((g ^ (lc & 7)) << 3)];
      bf8 kf1 = *(const bf8*)&k_lds[lc * 64 + (((4 + g) ^ (lc & 7)) << 3)];
#pragma unroll
      for (int s2 = 0; s2 < 2; ++s2) {
        sv[s2][t] = mfma16(kf0, qfA[s2], z);
        sv[s2][t] = mfma16(kf1, qfB[s2], sv[s2][t]);
      }
    }

    // p = exp2(s'); pack B-frags in-lane
    bf8 pb[2][2];
#pragma unroll
    for (int s2 = 0; s2 < 2; ++s2) {
      float acc_l = 0.f;
#pragma unroll
      for (int t = 0; t < 4; ++t) {
        float p0 = exp2f(sv[s2][t][0]);
        float p1 = exp2f(sv[s2][t][1]);
        float p2 = exp2f(sv[s2][t][2]);
        float p3 = exp2f(sv[s2][t][3]);
        acc_l += (p0 + p1) + (p2 + p3);
        int c = t >> 1, hb = (t & 1) * 4;
        pb[s2][c][hb + 0] = f2bf(p0);
        pb[s2][c][hb + 1] = f2bf(p1);
        pb[s2][c][hb + 2] = f2bf(p2);
        pb[s2][c][hb + 3] = f2bf(p3);
      }
      lsum_l[s2] += acc_l;
    }

    // O^T += V^T P
#pragma unroll
    for (int dt = 0; dt < 4; ++dt) {
      int d = dt * 16 + lr;
      bf8 vf0 = *(const bf8*)&v_lds[d * 72 + 8 * g];
      bf8 vf1 = *(const bf8*)&v_lds[d * 72 + 32 + 8 * g];
      oaccT[0][dt] = mfma16(vf0, pb[0][0], oaccT[0][dt]);
      oaccT[0][dt] = mfma16(vf1, pb[0][1], oaccT[0][dt]);
      oaccT[1][dt] = mfma16(vf0, pb[1][0], oaccT[1][dt]);
      oaccT[1][dt] = mfma16(vf1, pb[1][1], oaccT[1][dt]);
    }
  }

  // epilogue: bf16 unnormalized O partials + f32 exp-sum partials
#pragma unroll
  for (int s2 = 0; s2 < 2; ++s2) {
    int prow = (bb * 8 + h) * 1024 + qt * 128 + w * 32 + s2 * 16 + lr;
    short* ob = opart + ((size_t)split * 16384 + prow) * 64;
#pragma unroll
    for (int dt = 0; dt < 4; ++dt) {
      bf4 o4;
#pragma unroll
      for (int r = 0; r < 4; ++r) o4[r] = f2bf(oaccT[s2][dt][r]);
      *(bf4*)&ob[dt * 16 + 4 * g] = o4;
    }
    float t = lsum_l[s2];
    t += __shfl_xor(t, 16);
    t += __shfl_xor(t, 32);
    if (g == 0) lpart[(size_t)split * 16384 + prow] = t;
  }

  // ---- fused combine: last split block normalizes the group's 128 rows
  __syncthreads();
  if (tid == 0) { __threadfence(); s_old = atomicAdd(&cnt[gidc], 1); }
  __syncthreads();
  if (s_old != nsplit - 1) return;
  __threadfence();

  const int prow_grp = (bb * 8 + h) * 1024 + qt * 128;
  const int d4 = (tid & 15) * 4, rl0 = tid >> 4;
#pragma unroll
  for (int pass = 0; pass < 8; ++pass) {
    int rl = rl0 + pass * 16;
    int prow = prow_grp + rl;
    float l = 0.f;
    for (int s = 0; s < nsplit; ++s) l += lpart[(size_t)s * 16384 + prow];
    float o0 = 0.f, o1v = 0.f, o2v = 0.f, o3v = 0.f;
    for (int s = 0; s < nsplit; ++s) {
      bf4 v = *(const bf4*)&opart[((size_t)s * 16384 + prow) * 64 + d4];
      o0 += bf2f(v[0]); o1v += bf2f(v[1]); o2v += bf2f(v[2]); o3v += bf2f(v[3]);
    }
    float rle = 1.f / l;
    bf4 o;
    o[0] = f2bf(o0 * rle); o[1] = f2bf(o1v * rle);
    o[2] = f2bf(o2v * rle); o[3] = f2bf(o3v * rle);
    *(bf4*)&cat[(size_t)(bb * 1024 + qt * 128 + rl) * 1536 + ocol + h * 64 + d4] = o;
  }
}

// ---------------------------------------------------------------- GEMM (outproj, dbuf, bf16 W^T)
// C[2048,512] = cat[2048,1536] @ W + bias ; tile 64x64; XCD-swizzled 1-D grid of 256
__global__ __launch_bounds__(256) void gemmo_k(
    const short* __restrict__ A, const short* __restrict__ wT,
    const float* __restrict__ bias, float* __restrict__ out)
{
  __shared__ __align__(16) short a_lds[2][64 * 40];
  __shared__ __align__(16) short b_lds[2][64 * 40];
  const int tid = threadIdx.x;
  const int w = tid >> 6, lane = tid & 63, g = lane >> 4, lr = lane & 15;
  const int id = blockIdx.x;
  const int m = ((id >> 3) & 3) | ((id & 7) << 2);
  const int n = id >> 5;
  const int m0 = m * 64, n0 = n * 64;
  const int K = 1536;

  f32x4 z = {0.f, 0.f, 0.f, 0.f};
  f32x4 acc[4];
#pragma unroll
  for (int mi = 0; mi < 4; ++mi) acc[mi] = z;

  const int arow = tid >> 2, ac8 = tid & 3;
  const int bcol = tid & 63, bj4 = tid >> 6;
  bf8 ra, rna, rb, rnb;

  auto LOADAB = [&](int kg, bf8& ab, bf8& bb) {
    ab = *(const bf8*)&A[(size_t)(m0 + arow) * K + kg + ac8 * 8];
    bb = *(const bf8*)&wT[(size_t)(n0 + bcol) * K + kg + bj4 * 8];
  };
  auto STAGE = [&](int b, bf8 ab, bf8 bb) {
    *(bf8*)&a_lds[b][arow * 40 + ((ac8 ^ (arow & 3)) << 3)] = ab;
    *(bf8*)&b_lds[b][bcol * 40 + ((bj4 ^ (bcol & 3)) << 3)] = bb;
  };

  const int nit = K >> 5;
  LOADAB(0, ra, rb);
  STAGE(0, ra, rb);
  LOADAB(32, rna, rnb);
  __syncthreads();

  for (int it = 0; it < nit; ++it) {
    if (it + 1 < nit) STAGE((it + 1) & 1, rna, rnb);
    if (it + 2 < nit) LOADAB((it + 2) * 32, rna, rnb);

    const int b = it & 1;
    bf8 afr[4], bfr;
#pragma unroll
    for (int mi = 0; mi < 4; ++mi) {
      int row = mi * 16 + lr;
      afr[mi] = *(const bf8*)&a_lds[b][row * 40 + ((g ^ (row & 3)) << 3)];
    }
    {
      int col = w * 16 + lr;
      bfr = *(const bf8*)&b_lds[b][col * 40 + ((g ^ (col & 3)) << 3)];
    }
#pragma unroll
    for (int mi = 0; mi < 4; ++mi) acc[mi] = mfma16(afr[mi], bfr, acc[mi]);
    __syncthreads();
  }

  {
    int col = n0 + w * 16 + lr;
    float bv = bias[col];
#pragma unroll
    for (int mi = 0; mi < 4; ++mi) {
      int rowb = m0 + mi * 16 + g * 4;
#pragma unroll
      for (int r = 0; r < 4; ++r)
        out[(size_t)(rowb + r) * 512 + col] = acc[mi][r] + bv;
    }
  }
}

// ---------------------------------------------------------------- launch
extern "C" void kernel_launch(void* const* d_in, const int* in_sizes, int n_in,
                              void* d_out, int out_size, void* d_ws, size_t ws_size,
                              hipStream_t stream) {
  const float* x     = (const float*)d_in[0];
  const float* fore  = (const float*)d_in[1];
  const float* post  = (const float*)d_in[2];
  const float* wq    = (const float*)d_in[3];
  const float* bq    = (const float*)d_in[4];
  const float* wkv1  = (const float*)d_in[5];
  const float* bkv1  = (const float*)d_in[6];
  const float* wkv2  = (const float*)d_in[7];
  const float* bkv2  = (const float*)d_in[8];
  const float* wproj = (const float*)d_in[9];
  const float* bproj = (const float*)d_in[10];

  char* ws = (char*)d_ws;
  short* qb      = (short*)ws;                      // 2048*512  bf16 =  2 MB
  short* kv1     = (short*)(ws + (2ull << 20));     // 8192*1024 bf16 = 16 MB
  short* kv2     = (short*)(ws + (18ull << 20));    // 512*1024  bf16 =  1 MB
  short* cat     = (short*)(ws + (19ull << 20));    // 2048*1536 bf16 =  6 MB
  short* o1      = (short*)(ws + (25ull << 20));    // 8*16384*64 bf16 = 16 MB
  short* o2      = (short*)(ws + (41ull << 20));    // 4*16384*64 bf16 =  8 MB
  float* l1      = (float*)(ws + (49ull << 20));    // 8*16384 f32 = 512 KB
  float* l2      = (float*)(ws + (49ull << 20) + 524288);  // 256 KB
  float* qpart   = (float*)(ws + (50ull << 20));    // 2*2048*512 f32 = 8 MB
  float* kv2part = (float*)(ws + (58ull << 20));    // 4*512*1024 f32 = 8 MB
  short* wT      = (short*)(ws + (66ull << 20));    // 512*1536 bf16 = 1.5 MB
  int*   cnt     = (int*)(ws + (68ull << 20));      // 448 ints

  hipMemsetAsync(cnt, 0, 448 * sizeof(int), stream);
  mega1_k<<<1728, 256, 0, stream>>>(x, fore, post, wq, bq, wkv1, bkv1,
                                    wkv2, bkv2, wproj, kv1, cat,
                                    qpart, kv2part, qb, kv2, wT, cnt);
  attn_k<<<1536, 256, 0, stream>>>(qb, kv1, kv2, o1, l1, o2, l2, cat, cnt);
  gemmo_k<<<256, 256, 0, stream>>>(cat, wT, bproj, (float*)d_out);
}

// Round 8
// 93.171 us; speedup vs baseline: 2.7106x; 2.7106x over previous
//
#include <hip/hip_runtime.h>
#include <hip/hip_bf16.h>
#include <stdint.h>

typedef __attribute__((ext_vector_type(8))) short bf8;   // 8 bf16 (4 VGPR)
typedef __attribute__((ext_vector_type(4))) short bf4;
typedef __attribute__((ext_vector_type(2))) short bf2;
typedef __attribute__((ext_vector_type(4))) float f32x4;

__device__ inline short f2bf(float f) {
  union { __hip_bfloat16 h; short s; } u;
  u.h = __float2bfloat16(f);
  return u.s;
}
__device__ inline float bf2f(short s) {
  union { short s; __hip_bfloat16 h; } u;
  u.s = s;
  return __bfloat162float(u.h);
}

__device__ inline f32x4 mfma16(bf8 a, bf8 b, f32x4 c) {
  return __builtin_amdgcn_mfma_f32_16x16x32_bf16(a, b, c, 0, 0, 0);
}

// ---------------------------------------------------------------- mega kernel 1
// 1728 blocks, no cross-block sync:
//  bid <1024 : kv1 gemm (64m x 16n), K=256, bf16 out + bias
//  bid <1280 : qproj (16m x 8n x 2 kchunks) -> f32 partials (+x->cat copy)
//  bid <1536 : kv2 (4m x 16n x 4 kchunks) -> f32 partials
//  else      : wT[512][1536] = transpose(wproj) bf16 (192 blocks)
__global__ __launch_bounds__(256) void mega1_k(
    const float* __restrict__ x, const float* __restrict__ fore,
    const float* __restrict__ post,
    const float* __restrict__ wq, const float* __restrict__ wkv1,
    const float* __restrict__ bkv1, const float* __restrict__ wkv2,
    const float* __restrict__ wproj,
    short* __restrict__ kv1, short* __restrict__ cat,
    float* __restrict__ qpart, float* __restrict__ kv2part,
    short* __restrict__ wT)
{
  __shared__ __align__(16) short a_lds[2][128 * 40];
  __shared__ __align__(16) short b_lds[2][64 * 40];
  const int bid = blockIdx.x, tid = threadIdx.x;

  if (bid >= 1536) {                     // ---- wproj transpose
    float (*tl)[65] = reinterpret_cast<float(*)[65]>(&a_lds[0][0]);
    int tb = bid - 1536;                 // 0..191
    int kt = tb % 24, nt = tb / 24;
    int k0 = kt * 64, n0 = nt * 64;
    int kr = tid >> 2, c4 = tid & 3;
#pragma unroll
    for (int i = 0; i < 4; ++i) {
      int cc = c4 + i * 4;
      float4 v = *(const float4*)&wproj[(size_t)(k0 + kr) * 512 + n0 + cc * 4];
      tl[kr][cc * 4 + 0] = v.x; tl[kr][cc * 4 + 1] = v.y;
      tl[kr][cc * 4 + 2] = v.z; tl[kr][cc * 4 + 3] = v.w;
    }
    __syncthreads();
    int nr = tid >> 2, p = tid & 3;
#pragma unroll
    for (int i = 0; i < 2; ++i) {
      int kk = p * 16 + i * 8;
      bf8 o;
#pragma unroll
      for (int j = 0; j < 8; ++j) o[j] = f2bf(tl[kk + j][nr]);
      *(bf8*)&wT[(size_t)(n0 + nr) * 1536 + k0 + kk] = o;
    }
    return;
  }

  const float *A, *W, *bias = nullptr;
  short* out = nullptr;
  float* outf = nullptr;
  int N, lda, ldo, m0, n0, koff;
  bool wcat = false, bf16out;
  if (bid < 1024) {          // kv1
    A = fore; W = wkv1; bias = bkv1; out = kv1;
    N = 1024; lda = 256; ldo = 1024; koff = 0;
    m0 = (bid >> 4) * 128; n0 = (bid & 15) * 64; bf16out = true;
  } else if (bid < 1280) {   // qproj
    int j = bid - 1024; int kc = j >> 7; j &= 127;
    A = x; W = wq; outf = qpart + (size_t)kc * (2048 * 512);
    N = 512; lda = 512; ldo = 512; koff = kc * 256;
    m0 = (j >> 3) * 128; n0 = (j & 7) * 64; bf16out = false;
    wcat = (j & 7) == 0;
  } else {                   // kv2
    int j = bid - 1280; int kc = j >> 6; j &= 63;
    A = post; W = wkv2; outf = kv2part + (size_t)kc * (512 * 1024);
    N = 1024; lda = 1024; ldo = 1024; koff = kc * 256;
    m0 = (j >> 4) * 128; n0 = (j & 15) * 64; bf16out = false;
  }

  const int w = tid >> 6, lane = tid & 63, g = lane >> 4, lr = lane & 15;
  const int wrow = w & 1, wcol = w >> 1;

  f32x4 z = {0.f, 0.f, 0.f, 0.f};
  f32x4 acc[4][2];
#pragma unroll
  for (int mi = 0; mi < 4; ++mi)
#pragma unroll
    for (int ni = 0; ni < 2; ++ni) acc[mi][ni] = z;

  const int arow = tid >> 3, ac4 = tid & 7;
  const int bcol = tid & 63, bj4 = tid >> 6;

  float4 ra[4], rna[4];
  float rw[8], rnw[8];

  auto LOADA = [&](int kg, float4* af, float* wg) {
#pragma unroll
    for (int i = 0; i < 4; ++i)
      af[i] = *(const float4*)&A[(size_t)(m0 + arow + 32 * i) * lda + kg + ac4 * 4];
#pragma unroll
    for (int j = 0; j < 8; ++j)
      wg[j] = W[(size_t)(kg + bj4 * 8 + j) * N + n0 + bcol];
  };
  auto STAGE = [&](int b, const float4* af, const float* wg, int kg) {
#pragma unroll
    for (int i = 0; i < 4; ++i) {
      int rr = arow + 32 * i;
      int s = (ac4 >> 1) ^ (rr & 3);
      bf4 o;
      o[0] = f2bf(af[i].x); o[1] = f2bf(af[i].y);
      o[2] = f2bf(af[i].z); o[3] = f2bf(af[i].w);
      *(bf4*)&a_lds[b][rr * 40 + s * 8 + (ac4 & 1) * 4] = o;
      if (wcat)
        *(bf4*)&cat[(size_t)(m0 + rr) * 1536 + kg + ac4 * 4] = o;
    }
    int s = bj4 ^ (bcol & 3);
    bf8 o;
#pragma unroll
    for (int j = 0; j < 8; ++j) o[j] = f2bf(wg[j]);
    *(bf8*)&b_lds[b][bcol * 40 + s * 8] = o;
  };

  LOADA(koff, ra, rw);
  STAGE(0, ra, rw, koff);
  LOADA(koff + 32, rna, rnw);
  __syncthreads();

#pragma unroll
  for (int it = 0; it < 8; ++it) {
    if (it < 7) STAGE((it + 1) & 1, rna, rnw, koff + (it + 1) * 32);
    if (it < 6) LOADA(koff + (it + 2) * 32, rna, rnw);

    const int b = it & 1;
    bf8 afr[4], bfr[2];
#pragma unroll
    for (int mi = 0; mi < 4; ++mi) {
      int row = wrow * 64 + mi * 16 + lr;
      afr[mi] = *(const bf8*)&a_lds[b][row * 40 + ((g ^ (row & 3)) << 3)];
    }
#pragma unroll
    for (int ni = 0; ni < 2; ++ni) {
      int col = wcol * 32 + ni * 16 + lr;
      bfr[ni] = *(const bf8*)&b_lds[b][col * 40 + ((g ^ (col & 3)) << 3)];
    }
#pragma unroll
    for (int mi = 0; mi < 4; ++mi)
#pragma unroll
      for (int ni = 0; ni < 2; ++ni)
        acc[mi][ni] = mfma16(afr[mi], bfr[ni], acc[mi][ni]);
    __syncthreads();
  }

#pragma unroll
  for (int ni = 0; ni < 2; ++ni) {
    int col = n0 + wcol * 32 + ni * 16 + lr;
    float bv = bf16out ? bias[col] : 0.f;
#pragma unroll
    for (int mi = 0; mi < 4; ++mi) {
      int rowb = m0 + wrow * 64 + mi * 16 + g * 4;
#pragma unroll
      for (int r = 0; r < 4; ++r) {
        float val = acc[mi][ni][r] + bv;
        if (bf16out)
          out[(size_t)(rowb + r) * ldo + col] = f2bf(val);
        else
          outf[(size_t)(rowb + r) * ldo + col] = val;
      }
    }
  }
}

// ---------------------------------------------------------------- finalize split-K partials
// bid<1024: qb = bf16((qp0+qp1+bq)*0.125*log2e) ; else kv2 = bf16(sum4+bkv2)
__global__ __launch_bounds__(256) void finalize_k(
    const float* __restrict__ qpart, const float* __restrict__ kv2part,
    const float* __restrict__ bq, const float* __restrict__ bkv2,
    short* __restrict__ qb, short* __restrict__ kv2)
{
  const int bid = blockIdx.x, tid = threadIdx.x;
  if (bid < 1024) {
    int i = bid * 256 + tid;
    const float qsc = 0.125f * 1.44269504088896f;
    float4 a = ((const float4*)qpart)[i];
    float4 b = ((const float4*)qpart)[i + 262144];
    int col = (i * 4) & 511;
    float4 bv = *(const float4*)&bq[col];
    bf4 o;
    o[0] = f2bf((a.x + b.x + bv.x) * qsc);
    o[1] = f2bf((a.y + b.y + bv.y) * qsc);
    o[2] = f2bf((a.z + b.z + bv.z) * qsc);
    o[3] = f2bf((a.w + b.w + bv.w) * qsc);
    ((bf4*)qb)[i] = o;
  } else {
    int j = (bid - 1024) * 256 + tid;
    float4 a = ((const float4*)kv2part)[j];
    float4 b = ((const float4*)kv2part)[j + 131072];
    float4 c = ((const float4*)kv2part)[j + 262144];
    float4 d = ((const float4*)kv2part)[j + 393216];
    int col = (j * 4) & 1023;
    float4 bv = *(const float4*)&bkv2[col];
    bf4 o;
    o[0] = f2bf(a.x + b.x + c.x + d.x + bv.x);
    o[1] = f2bf(a.y + b.y + c.y + d.y + bv.y);
    o[2] = f2bf(a.z + b.z + c.z + d.z + bv.z);
    o[3] = f2bf(a.w + b.w + c.w + d.w + bv.w);
    ((bf4*)kv2)[j] = o;
  }
}

// ---------------------------------------------------------------- attention
// bid<512: attn1 (kv1, chunk 1024, nsplit 4) -> bf16 O partials + f32 l partials
// bid>=512: attn2 (kv2, full 256, nsplit 1) -> normalized, direct to cat
// XCD-friendly decode: kv-chunk sharers and split-group members are bid%8-aligned.
__global__ __launch_bounds__(256) void attn_k(
    const short* __restrict__ q,
    const short* __restrict__ kv1, const short* __restrict__ kv2,
    short* __restrict__ o1, float* __restrict__ l1,
    short* __restrict__ cat)
{
  __shared__ __align__(16) short k_lds[64 * 64];   // [lc][d] XOR-swizzled octets
  __shared__ __align__(16) short v_lds[64 * 72];   // [d][lc-permuted]
  const int tid = threadIdx.x;
  const int w = tid >> 6, lane = tid & 63, g = lane >> 4, lr = lane & 15;

  const int bid = blockIdx.x;
  const short* kvsrc;
  int qt, h, bb, split, chunk, Lc;
  bool direct;
  if (bid < 512) {
    qt = bid >> 6; int j = bid & 63;
    h = j & 7; int zz = j >> 3;
    bb = zz >> 2; split = zz & 3;
    kvsrc = kv1; chunk = 1024; Lc = 4096; direct = false;
  } else {
    int j2 = bid - 512;
    qt = j2 >> 4; int r = j2 & 15;
    h = r & 7; bb = r >> 3; split = 0;
    kvsrc = kv2; chunk = 256; Lc = 256; direct = true;
  }

  // Q: 32 rows per wave, 2 sets of 16 (B-operand fragments)
  const int qbase = bb * 1024 + qt * 128 + w * 32;
  bf8 qfA[2], qfB[2];
#pragma unroll
  for (int s2 = 0; s2 < 2; ++s2) {
    const short* qp = &q[(size_t)(qbase + s2 * 16 + lr) * 512 + h * 64];
    qfA[s2] = *(const bf8*)&qp[g * 8];
    qfB[s2] = *(const bf8*)&qp[32 + g * 8];
  }

  const f32x4 z = {0.f, 0.f, 0.f, 0.f};
  f32x4 oaccT[2][4];   // [set][dt] : O^T rows d=16dt+4g+r, col q=lr
#pragma unroll
  for (int s2 = 0; s2 < 2; ++s2)
#pragma unroll
    for (int i = 0; i < 4; ++i) oaccT[s2][i] = z;
  float lsum_l[2] = {0.f, 0.f};

  const short* kvb = kvsrc + (size_t)bb * Lc * 1024 + (size_t)split * chunk * 1024;

  const int krow = tid >> 2, ksl = tid & 3;
  const short* kgp = kvb + (size_t)krow * 1024 + h * 64;
  const int vi = tid & 31, vj = tid >> 5;
  const short* vgp = kvb + (size_t)(2 * vi) * 1024 + 512 + h * 64 + vj * 8;
  const int lc0 = 2 * vi;
  const int vpos = (lc0 & 32) + ((lc0 & 12) << 1) + ((lc0 & 16) >> 2) + (lc0 & 3);

  bf8 k0c, k1c, v0c, v1c;
  k0c = *(const bf8*)(kgp + ksl * 8);
  k1c = *(const bf8*)(kgp + (ksl + 4) * 8);
  v0c = *(const bf8*)vgp;
  v1c = *(const bf8*)(vgp + 1024);

  const int nit = chunk >> 6;
  for (int it = 0; it < nit; ++it) {
    __syncthreads();
    *(bf8*)&k_lds[krow * 64 + ((ksl ^ (krow & 7)) << 3)] = k0c;
    *(bf8*)&k_lds[krow * 64 + (((ksl + 4) ^ (krow & 7)) << 3)] = k1c;
#pragma unroll
    for (int jj = 0; jj < 8; ++jj) {
      int d = vj * 8 + jj;
      bf2 pr; pr[0] = v0c[jj]; pr[1] = v1c[jj];
      *(bf2*)&v_lds[d * 72 + vpos] = pr;
    }
    __syncthreads();
    if (it + 1 < nit) {
      size_t off = (size_t)64 * 1024 * (it + 1);
      k0c = *(const bf8*)(kgp + off + ksl * 8);
      k1c = *(const bf8*)(kgp + off + (ksl + 4) * 8);
      v0c = *(const bf8*)(vgp + off);
      v1c = *(const bf8*)(vgp + off + 1024);
    }

    // S^T = (K Q^T) ; q prescaled by 0.125*log2e so p = exp2(s')
    f32x4 sv[2][4];
#pragma unroll
    for (int t = 0; t < 4; ++t) {
      int lc = t * 16 + lr;
      bf8 kf0 = *(const bf8*)&k_lds[lc * 64 + ((g ^ (lc & 7)) << 3)];
      bf8 kf1 = *(const bf8*)&k_lds[lc * 64 + (((4 + g) ^ (lc & 7)) << 3)];
#pragma unroll
      for (int s2 = 0; s2 < 2; ++s2) {
        sv[s2][t] = mfma16(kf0, qfA[s2], z);
        sv[s2][t] = mfma16(kf1, qfB[s2], sv[s2][t]);
      }
    }

    // p = exp2(s'); pack B-frags in-lane
    bf8 pb[2][2];
#pragma unroll
    for (int s2 = 0; s2 < 2; ++s2) {
      float acc_l = 0.f;
#pragma unroll
      for (int t = 0; t < 4; ++t) {
        float p0 = exp2f(sv[s2][t][0]);
        float p1 = exp2f(sv[s2][t][1]);
        float p2 = exp2f(sv[s2][t][2]);
        float p3 = exp2f(sv[s2][t][3]);
        acc_l += (p0 + p1) + (p2 + p3);
        int c = t >> 1, hb = (t & 1) * 4;
        pb[s2][c][hb + 0] = f2bf(p0);
        pb[s2][c][hb + 1] = f2bf(p1);
        pb[s2][c][hb + 2] = f2bf(p2);
        pb[s2][c][hb + 3] = f2bf(p3);
      }
      lsum_l[s2] += acc_l;
    }

    // O^T += V^T P
#pragma unroll
    for (int dt = 0; dt < 4; ++dt) {
      int d = dt * 16 + lr;
      bf8 vf0 = *(const bf8*)&v_lds[d * 72 + 8 * g];
      bf8 vf1 = *(const bf8*)&v_lds[d * 72 + 32 + 8 * g];
      oaccT[0][dt] = mfma16(vf0, pb[0][0], oaccT[0][dt]);
      oaccT[0][dt] = mfma16(vf1, pb[0][1], oaccT[0][dt]);
      oaccT[1][dt] = mfma16(vf0, pb[1][0], oaccT[1][dt]);
      oaccT[1][dt] = mfma16(vf1, pb[1][1], oaccT[1][dt]);
    }
  }

  if (direct) {
    // normalize in-register, write straight to cat (column block 1024..1535)
#pragma unroll
    for (int s2 = 0; s2 < 2; ++s2) {
      float t = lsum_l[s2];
      t += __shfl_xor(t, 16);
      t += __shfl_xor(t, 32);
      float rle = 1.f / t;
      int qrow = qbase + s2 * 16 + lr;
#pragma unroll
      for (int dt = 0; dt < 4; ++dt) {
        bf4 o4;
#pragma unroll
        for (int r = 0; r < 4; ++r) o4[r] = f2bf(oaccT[s2][dt][r] * rle);
        *(bf4*)&cat[(size_t)qrow * 1536 + 1024 + h * 64 + dt * 16 + 4 * g] = o4;
      }
    }
    return;
  }

  // region1 epilogue: bf16 unnormalized O partials + f32 exp-sum partials
#pragma unroll
  for (int s2 = 0; s2 < 2; ++s2) {
    int prow = (bb * 8 + h) * 1024 + qt * 128 + w * 32 + s2 * 16 + lr;
    short* ob = o1 + ((size_t)split * 16384 + prow) * 64;
#pragma unroll
    for (int dt = 0; dt < 4; ++dt) {
      bf4 o4;
#pragma unroll
      for (int r = 0; r < 4; ++r) o4[r] = f2bf(oaccT[s2][dt][r]);
      *(bf4*)&ob[dt * 16 + 4 * g] = o4;
    }
    float t = lsum_l[s2];
    t += __shfl_xor(t, 16);
    t += __shfl_xor(t, 32);
    if (g == 0) l1[(size_t)split * 16384 + prow] = t;
  }
}

// ---------------------------------------------------------------- combine region1 partials
// 512 blocks; 8 threads per row (bf8 of d), 32 rows/block
__global__ __launch_bounds__(256) void comb_k(
    const short* __restrict__ o1, const float* __restrict__ l1,
    short* __restrict__ cat)
{
  int row = blockIdx.x * 32 + (threadIdx.x >> 3);
  int d8 = (threadIdx.x & 7) * 8;
  float l = 0.f;
#pragma unroll
  for (int s = 0; s < 4; ++s) l += l1[(size_t)s * 16384 + row];
  float acc[8] = {};
#pragma unroll
  for (int s = 0; s < 4; ++s) {
    bf8 v = *(const bf8*)&o1[((size_t)s * 16384 + row) * 64 + d8];
#pragma unroll
    for (int j = 0; j < 8; ++j) acc[j] += bf2f(v[j]);
  }
  float rle = 1.f / l;
  bf8 o;
#pragma unroll
  for (int j = 0; j < 8; ++j) o[j] = f2bf(acc[j] * rle);
  int bb = row >> 13, h = (row >> 10) & 7, qr = row & 1023;
  *(bf8*)&cat[(size_t)(bb * 1024 + qr) * 1536 + 512 + h * 64 + d8] = o;
}

// ---------------------------------------------------------------- GEMM (outproj, dbuf, bf16 W^T)
// C[2048,512] = cat[2048,1536] @ W + bias ; tile 64x64; XCD-swizzled 1-D grid of 256
__global__ __launch_bounds__(256) void gemmo_k(
    const short* __restrict__ A, const short* __restrict__ wT,
    const float* __restrict__ bias, float* __restrict__ out)
{
  __shared__ __align__(16) short a_lds[2][64 * 40];
  __shared__ __align__(16) short b_lds[2][64 * 40];
  const int tid = threadIdx.x;
  const int w = tid >> 6, lane = tid & 63, g = lane >> 4, lr = lane & 15;
  const int id = blockIdx.x;
  const int m = ((id >> 3) & 3) | ((id & 7) << 2);
  const int n = id >> 5;
  const int m0 = m * 64, n0 = n * 64;
  const int K = 1536;

  f32x4 z = {0.f, 0.f, 0.f, 0.f};
  f32x4 acc[4];
#pragma unroll
  for (int mi = 0; mi < 4; ++mi) acc[mi] = z;

  const int arow = tid >> 2, ac8 = tid & 3;
  const int bcol = tid & 63, bj4 = tid >> 6;
  bf8 ra, rna, rb, rnb;

  auto LOADAB = [&](int kg, bf8& ab, bf8& bb) {
    ab = *(const bf8*)&A[(size_t)(m0 + arow) * K + kg + ac8 * 8];
    bb = *(const bf8*)&wT[(size_t)(n0 + bcol) * K + kg + bj4 * 8];
  };
  auto STAGE = [&](int b, bf8 ab, bf8 bb) {
    *(bf8*)&a_lds[b][arow * 40 + ((ac8 ^ (arow & 3)) << 3)] = ab;
    *(bf8*)&b_lds[b][bcol * 40 + ((bj4 ^ (bcol & 3)) << 3)] = bb;
  };

  const int nit = K >> 5;
  LOADAB(0, ra, rb);
  STAGE(0, ra, rb);
  LOADAB(32, rna, rnb);
  __syncthreads();

  for (int it = 0; it < nit; ++it) {
    if (it + 1 < nit) STAGE((it + 1) & 1, rna, rnb);
    if (it + 2 < nit) LOADAB((it + 2) * 32, rna, rnb);

    const int b = it & 1;
    bf8 afr[4], bfr;
#pragma unroll
    for (int mi = 0; mi < 4; ++mi) {
      int row = mi * 16 + lr;
      afr[mi] = *(const bf8*)&a_lds[b][row * 40 + ((g ^ (row & 3)) << 3)];
    }
    {
      int col = w * 16 + lr;
      bfr = *(const bf8*)&b_lds[b][col * 40 + ((g ^ (col & 3)) << 3)];
    }
#pragma unroll
    for (int mi = 0; mi < 4; ++mi) acc[mi] = mfma16(afr[mi], bfr, acc[mi]);
    __syncthreads();
  }

  {
    int col = n0 + w * 16 + lr;
    float bv = bias[col];
#pragma unroll
    for (int mi = 0; mi < 4; ++mi) {
      int rowb = m0 + mi * 16 + g * 4;
#pragma unroll
      for (int r = 0; r < 4; ++r)
        out[(size_t)(rowb + r) * 512 + col] = acc[mi][r] + bv;
    }
  }
}

// ---------------------------------------------------------------- launch
extern "C" void kernel_launch(void* const* d_in, const int* in_sizes, int n_in,
                              void* d_out, int out_size, void* d_ws, size_t ws_size,
                              hipStream_t stream) {
  const float* x     = (const float*)d_in[0];
  const float* fore  = (const float*)d_in[1];
  const float* post  = (const float*)d_in[2];
  const float* wq    = (const float*)d_in[3];
  const float* bq    = (const float*)d_in[4];
  const float* wkv1  = (const float*)d_in[5];
  const float* bkv1  = (const float*)d_in[6];
  const float* wkv2  = (const float*)d_in[7];
  const float* bkv2  = (const float*)d_in[8];
  const float* wproj = (const float*)d_in[9];
  const float* bproj = (const float*)d_in[10];

  char* ws = (char*)d_ws;
  short* qb      = (short*)ws;                      // 2048*512  bf16 =  2 MB
  short* kv1     = (short*)(ws + (2ull << 20));     // 8192*1024 bf16 = 16 MB
  short* kv2     = (short*)(ws + (18ull << 20));    // 512*1024  bf16 =  1 MB
  short* cat     = (short*)(ws + (19ull << 20));    // 2048*1536 bf16 =  6 MB
  short* o1      = (short*)(ws + (25ull << 20));    // 4*16384*64 bf16 = 8 MB
  float* l1      = (float*)(ws + (33ull << 20));    // 4*16384 f32 = 256 KB
  float* qpart   = (float*)(ws + (34ull << 20));    // 2*2048*512 f32 = 8 MB
  float* kv2part = (float*)(ws + (42ull << 20));    // 4*512*1024 f32 = 8 MB
  short* wT      = (short*)(ws + (50ull << 20));    // 512*1536 bf16 = 1.5 MB

  mega1_k<<<1728, 256, 0, stream>>>(x, fore, post, wq, wkv1, bkv1, wkv2,
                                    wproj, kv1, cat, qpart, kv2part, wT);
  finalize_k<<<1536, 256, 0, stream>>>(qpart, kv2part, bq, bkv2, qb, kv2);
  attn_k<<<640, 256, 0, stream>>>(qb, kv1, kv2, o1, l1, cat);
  comb_k<<<512, 256, 0, stream>>>(o1, l1, cat);
  gemmo_k<<<256, 256, 0, stream>>>(cat, wT, bproj, (float*)d_out);
}

// Round 9
// 86.054 us; speedup vs baseline: 2.9348x; 1.0827x over previous
//
#include <hip/hip_runtime.h>
#include <hip/hip_bf16.h>
#include <stdint.h>

typedef __attribute__((ext_vector_type(8))) short bf8;   // 8 bf16 (4 VGPR)
typedef __attribute__((ext_vector_type(4))) short bf4;
typedef __attribute__((ext_vector_type(2))) short bf2;
typedef __attribute__((ext_vector_type(4))) float f32x4;

__device__ inline short f2bf(float f) {
  union { __hip_bfloat16 h; short s; } u;
  u.h = __float2bfloat16(f);
  return u.s;
}
__device__ inline float bf2f(short s) {
  union { short s; __hip_bfloat16 h; } u;
  u.s = s;
  return __bfloat162float(u.h);
}

__device__ inline f32x4 mfma16(bf8 a, bf8 b, f32x4 c) {
  return __builtin_amdgcn_mfma_f32_16x16x32_bf16(a, b, c, 0, 0, 0);
}

// ---------------------------------------------------------------- mega kernel 1
// 1408 blocks, longest-first (LPT) ordering, no split-K, no cross-block sync:
//  bid <64   : kv2   gemm K=1024 (4m x 16n)  -> bf16 + bias
//  bid <192  : qproj gemm K=512  (16m x 8n)  -> bf16 (bias+0.125*log2e scale)
//              (+ x->cat bf16 copy on n0==0 blocks)
//  bid <1216 : kv1   gemm K=256  (64m x 16n) -> bf16 + bias
//  else      : wT[512][1536] = transpose(wproj) bf16 (192 blocks)
__global__ __launch_bounds__(256) void mega1_k(
    const float* __restrict__ x, const float* __restrict__ fore,
    const float* __restrict__ post,
    const float* __restrict__ wq, const float* __restrict__ bq,
    const float* __restrict__ wkv1, const float* __restrict__ bkv1,
    const float* __restrict__ wkv2, const float* __restrict__ bkv2,
    const float* __restrict__ wproj,
    short* __restrict__ qb, short* __restrict__ kv1, short* __restrict__ kv2,
    short* __restrict__ cat, short* __restrict__ wT)
{
  __shared__ __align__(16) short a_lds[2][128 * 40];
  __shared__ __align__(16) short b_lds[2][64 * 40];
  const int bid = blockIdx.x, tid = threadIdx.x;

  if (bid >= 1216) {                     // ---- wproj transpose
    float (*tl)[65] = reinterpret_cast<float(*)[65]>(&a_lds[0][0]);
    int tb = bid - 1216;                 // 0..191
    int kt = tb % 24, nt = tb / 24;
    int k0 = kt * 64, n0 = nt * 64;
    int kr = tid >> 2, c4 = tid & 3;
#pragma unroll
    for (int i = 0; i < 4; ++i) {
      int cc = c4 + i * 4;
      float4 v = *(const float4*)&wproj[(size_t)(k0 + kr) * 512 + n0 + cc * 4];
      tl[kr][cc * 4 + 0] = v.x; tl[kr][cc * 4 + 1] = v.y;
      tl[kr][cc * 4 + 2] = v.z; tl[kr][cc * 4 + 3] = v.w;
    }
    __syncthreads();
    int nr = tid >> 2, p = tid & 3;
#pragma unroll
    for (int i = 0; i < 2; ++i) {
      int kk = p * 16 + i * 8;
      bf8 o;
#pragma unroll
      for (int j = 0; j < 8; ++j) o[j] = f2bf(tl[kk + j][nr]);
      *(bf8*)&wT[(size_t)(n0 + nr) * 1536 + k0 + kk] = o;
    }
    return;
  }

  const float *A, *W, *bias;
  short* out;
  int N, lda, ldo, m0, n0, K;
  float osc = 1.f;
  bool wcat = false;
  if (bid < 64) {            // kv2: M=512 N=1024 K=1024 (longest first)
    A = post; W = wkv2; bias = bkv2; out = kv2;
    N = 1024; lda = 1024; ldo = 1024; K = 1024;
    m0 = (bid >> 4) * 128; n0 = (bid & 15) * 64;
  } else if (bid < 192) {    // qproj: M=2048 N=512 K=512
    int j = bid - 64;
    A = x; W = wq; bias = bq; out = qb;
    N = 512; lda = 512; ldo = 512; K = 512;
    m0 = (j >> 3) * 128; n0 = (j & 7) * 64;
    osc = 0.125f * 1.44269504088896f;
    wcat = (j & 7) == 0;
  } else {                   // kv1: M=8192 N=1024 K=256
    int j = bid - 192;
    A = fore; W = wkv1; bias = bkv1; out = kv1;
    N = 1024; lda = 256; ldo = 1024; K = 256;
    m0 = (j >> 4) * 128; n0 = (j & 15) * 64;
  }

  const int w = tid >> 6, lane = tid & 63, g = lane >> 4, lr = lane & 15;
  const int wrow = w & 1, wcol = w >> 1;

  f32x4 z = {0.f, 0.f, 0.f, 0.f};
  f32x4 acc[4][2];
#pragma unroll
  for (int mi = 0; mi < 4; ++mi)
#pragma unroll
    for (int ni = 0; ni < 2; ++ni) acc[mi][ni] = z;

  const int arow = tid >> 3, ac4 = tid & 7;
  const int bcol = tid & 63, bj4 = tid >> 6;

  float4 ra[4], rna[4];
  float rw[8], rnw[8];

  auto LOADA = [&](int kg, float4* af, float* wg) {
#pragma unroll
    for (int i = 0; i < 4; ++i)
      af[i] = *(const float4*)&A[(size_t)(m0 + arow + 32 * i) * lda + kg + ac4 * 4];
#pragma unroll
    for (int j = 0; j < 8; ++j)
      wg[j] = W[(size_t)(kg + bj4 * 8 + j) * N + n0 + bcol];
  };
  auto STAGE = [&](int b, const float4* af, const float* wg, int kg) {
#pragma unroll
    for (int i = 0; i < 4; ++i) {
      int rr = arow + 32 * i;
      int s = (ac4 >> 1) ^ (rr & 3);
      bf4 o;
      o[0] = f2bf(af[i].x); o[1] = f2bf(af[i].y);
      o[2] = f2bf(af[i].z); o[3] = f2bf(af[i].w);
      *(bf4*)&a_lds[b][rr * 40 + s * 8 + (ac4 & 1) * 4] = o;
      if (wcat)
        *(bf4*)&cat[(size_t)(m0 + rr) * 1536 + kg + ac4 * 4] = o;
    }
    int s = bj4 ^ (bcol & 3);
    bf8 o;
#pragma unroll
    for (int j = 0; j < 8; ++j) o[j] = f2bf(wg[j]);
    *(bf8*)&b_lds[b][bcol * 40 + s * 8] = o;
  };

  const int nit = K >> 5;
  LOADA(0, ra, rw);
  STAGE(0, ra, rw, 0);
  LOADA(32, rna, rnw);
  __syncthreads();

  for (int it = 0; it < nit; ++it) {
    if (it + 1 < nit) STAGE((it + 1) & 1, rna, rnw, (it + 1) * 32);
    if (it + 2 < nit) LOADA((it + 2) * 32, rna, rnw);

    const int b = it & 1;
    bf8 afr[4], bfr[2];
#pragma unroll
    for (int mi = 0; mi < 4; ++mi) {
      int row = wrow * 64 + mi * 16 + lr;
      afr[mi] = *(const bf8*)&a_lds[b][row * 40 + ((g ^ (row & 3)) << 3)];
    }
#pragma unroll
    for (int ni = 0; ni < 2; ++ni) {
      int col = wcol * 32 + ni * 16 + lr;
      bfr[ni] = *(const bf8*)&b_lds[b][col * 40 + ((g ^ (col & 3)) << 3)];
    }
#pragma unroll
    for (int mi = 0; mi < 4; ++mi)
#pragma unroll
      for (int ni = 0; ni < 2; ++ni)
        acc[mi][ni] = mfma16(afr[mi], bfr[ni], acc[mi][ni]);
    __syncthreads();
  }

#pragma unroll
  for (int ni = 0; ni < 2; ++ni) {
    int col = n0 + wcol * 32 + ni * 16 + lr;
    float bv = bias[col];
#pragma unroll
    for (int mi = 0; mi < 4; ++mi) {
      int rowb = m0 + wrow * 64 + mi * 16 + g * 4;
#pragma unroll
      for (int r = 0; r < 4; ++r)
        out[(size_t)(rowb + r) * ldo + col] = f2bf((acc[mi][ni][r] + bv) * osc);
    }
  }
}

// ---------------------------------------------------------------- attention
// bid<1024: attn1 (kv1, chunk 512, nsplit 8) -> bf16 O partials + f32 l partials
// bid>=1024: attn2 (kv2, full 256, nsplit 1) -> normalized, direct to cat
// Decode keeps kv-chunk sharers bid%8-aligned (same XCD L2).
__global__ __launch_bounds__(256) void attn_k(
    const short* __restrict__ q,
    const short* __restrict__ kv1, const short* __restrict__ kv2,
    short* __restrict__ o1, float* __restrict__ l1,
    short* __restrict__ cat)
{
  __shared__ __align__(16) short k_lds[64 * 64];   // [lc][d] XOR-swizzled octets
  __shared__ __align__(16) short v_lds[64 * 72];   // [d][lc-permuted]
  const int tid = threadIdx.x;
  const int w = tid >> 6, lane = tid & 63, g = lane >> 4, lr = lane & 15;

  const int bid = blockIdx.x;
  const short* kvsrc;
  int qt, h, bb, split, chunk, Lc;
  bool direct;
  if (bid < 1024) {
    qt = bid >> 7; int j = bid & 127;
    h = j & 7; int zz = j >> 3;
    bb = zz >> 3; split = zz & 7;
    kvsrc = kv1; chunk = 512; Lc = 4096; direct = false;
  } else {
    int j2 = bid - 1024;
    qt = j2 >> 4; int r = j2 & 15;
    h = r & 7; bb = r >> 3; split = 0;
    kvsrc = kv2; chunk = 256; Lc = 256; direct = true;
  }

  // Q: 32 rows per wave, 2 sets of 16 (B-operand fragments)
  const int qbase = bb * 1024 + qt * 128 + w * 32;
  bf8 qfA[2], qfB[2];
#pragma unroll
  for (int s2 = 0; s2 < 2; ++s2) {
    const short* qp = &q[(size_t)(qbase + s2 * 16 + lr) * 512 + h * 64];
    qfA[s2] = *(const bf8*)&qp[g * 8];
    qfB[s2] = *(const bf8*)&qp[32 + g * 8];
  }

  const f32x4 z = {0.f, 0.f, 0.f, 0.f};
  f32x4 oaccT[2][4];   // [set][dt] : O^T rows d=16dt+4g+r, col q=lr
#pragma unroll
  for (int s2 = 0; s2 < 2; ++s2)
#pragma unroll
    for (int i = 0; i < 4; ++i) oaccT[s2][i] = z;
  float lsum_l[2] = {0.f, 0.f};

  const short* kvb = kvsrc + (size_t)bb * Lc * 1024 + (size_t)split * chunk * 1024;

  const int krow = tid >> 2, ksl = tid & 3;
  const short* kgp = kvb + (size_t)krow * 1024 + h * 64;
  const int vi = tid & 31, vj = tid >> 5;
  const short* vgp = kvb + (size_t)(2 * vi) * 1024 + 512 + h * 64 + vj * 8;
  const int lc0 = 2 * vi;
  const int vpos = (lc0 & 32) + ((lc0 & 12) << 1) + ((lc0 & 16) >> 2) + (lc0 & 3);

  bf8 k0c, k1c, v0c, v1c;
  k0c = *(const bf8*)(kgp + ksl * 8);
  k1c = *(const bf8*)(kgp + (ksl + 4) * 8);
  v0c = *(const bf8*)vgp;
  v1c = *(const bf8*)(vgp + 1024);

  const int nit = chunk >> 6;
  for (int it = 0; it < nit; ++it) {
    __syncthreads();
    *(bf8*)&k_lds[krow * 64 + ((ksl ^ (krow & 7)) << 3)] = k0c;
    *(bf8*)&k_lds[krow * 64 + (((ksl + 4) ^ (krow & 7)) << 3)] = k1c;
#pragma unroll
    for (int jj = 0; jj < 8; ++jj) {
      int d = vj * 8 + jj;
      bf2 pr; pr[0] = v0c[jj]; pr[1] = v1c[jj];
      *(bf2*)&v_lds[d * 72 + vpos] = pr;
    }
    __syncthreads();
    if (it + 1 < nit) {
      size_t off = (size_t)64 * 1024 * (it + 1);
      k0c = *(const bf8*)(kgp + off + ksl * 8);
      k1c = *(const bf8*)(kgp + off + (ksl + 4) * 8);
      v0c = *(const bf8*)(vgp + off);
      v1c = *(const bf8*)(vgp + off + 1024);
    }

    // S^T = (K Q^T) ; q prescaled by 0.125*log2e so p = exp2(s')
    f32x4 sv[2][4];
#pragma unroll
    for (int t = 0; t < 4; ++t) {
      int lc = t * 16 + lr;
      bf8 kf0 = *(const bf8*)&k_lds[lc * 64 + ((g ^ (lc & 7)) << 3)];
      bf8 kf1 = *(const bf8*)&k_lds[lc * 64 + (((4 + g) ^ (lc & 7)) << 3)];
#pragma unroll
      for (int s2 = 0; s2 < 2; ++s2) {
        sv[s2][t] = mfma16(kf0, qfA[s2], z);
        sv[s2][t] = mfma16(kf1, qfB[s2], sv[s2][t]);
      }
    }

    // p = exp2(s'); pack B-frags in-lane
    bf8 pb[2][2];
#pragma unroll
    for (int s2 = 0; s2 < 2; ++s2) {
      float acc_l = 0.f;
#pragma unroll
      for (int t = 0; t < 4; ++t) {
        float p0 = exp2f(sv[s2][t][0]);
        float p1 = exp2f(sv[s2][t][1]);
        float p2 = exp2f(sv[s2][t][2]);
        float p3 = exp2f(sv[s2][t][3]);
        acc_l += (p0 + p1) + (p2 + p3);
        int c = t >> 1, hb = (t & 1) * 4;
        pb[s2][c][hb + 0] = f2bf(p0);
        pb[s2][c][hb + 1] = f2bf(p1);
        pb[s2][c][hb + 2] = f2bf(p2);
        pb[s2][c][hb + 3] = f2bf(p3);
      }
      lsum_l[s2] += acc_l;
    }

    // O^T += V^T P
#pragma unroll
    for (int dt = 0; dt < 4; ++dt) {
      int d = dt * 16 + lr;
      bf8 vf0 = *(const bf8*)&v_lds[d * 72 + 8 * g];
      bf8 vf1 = *(const bf8*)&v_lds[d * 72 + 32 + 8 * g];
      oaccT[0][dt] = mfma16(vf0, pb[0][0], oaccT[0][dt]);
      oaccT[0][dt] = mfma16(vf1, pb[0][1], oaccT[0][dt]);
      oaccT[1][dt] = mfma16(vf0, pb[1][0], oaccT[1][dt]);
      oaccT[1][dt] = mfma16(vf1, pb[1][1], oaccT[1][dt]);
    }
  }

  if (direct) {
    // normalize in-register, write straight to cat (column block 1024..1535)
#pragma unroll
    for (int s2 = 0; s2 < 2; ++s2) {
      float t = lsum_l[s2];
      t += __shfl_xor(t, 16);
      t += __shfl_xor(t, 32);
      float rle = 1.f / t;
      int qrow = qbase + s2 * 16 + lr;
#pragma unroll
      for (int dt = 0; dt < 4; ++dt) {
        bf4 o4;
#pragma unroll
        for (int r = 0; r < 4; ++r) o4[r] = f2bf(oaccT[s2][dt][r] * rle);
        *(bf4*)&cat[(size_t)qrow * 1536 + 1024 + h * 64 + dt * 16 + 4 * g] = o4;
      }
    }
    return;
  }

  // region1 epilogue: bf16 unnormalized O partials + f32 exp-sum partials
#pragma unroll
  for (int s2 = 0; s2 < 2; ++s2) {
    int prow = (bb * 8 + h) * 1024 + qt * 128 + w * 32 + s2 * 16 + lr;
    short* ob = o1 + ((size_t)split * 16384 + prow) * 64;
#pragma unroll
    for (int dt = 0; dt < 4; ++dt) {
      bf4 o4;
#pragma unroll
      for (int r = 0; r < 4; ++r) o4[r] = f2bf(oaccT[s2][dt][r]);
      *(bf4*)&ob[dt * 16 + 4 * g] = o4;
    }
    float t = lsum_l[s2];
    t += __shfl_xor(t, 16);
    t += __shfl_xor(t, 32);
    if (g == 0) l1[(size_t)split * 16384 + prow] = t;
  }
}

// ---------------------------------------------------------------- combine region1 partials
// 512 blocks; 8 threads per row (bf8 of d), 32 rows/block, 8 splits
__global__ __launch_bounds__(256) void comb_k(
    const short* __restrict__ o1, const float* __restrict__ l1,
    short* __restrict__ cat)
{
  int row = blockIdx.x * 32 + (threadIdx.x >> 3);
  int d8 = (threadIdx.x & 7) * 8;
  float l = 0.f;
#pragma unroll
  for (int s = 0; s < 8; ++s) l += l1[(size_t)s * 16384 + row];
  float acc[8] = {};
#pragma unroll
  for (int s = 0; s < 8; ++s) {
    bf8 v = *(const bf8*)&o1[((size_t)s * 16384 + row) * 64 + d8];
#pragma unroll
    for (int j = 0; j < 8; ++j) acc[j] += bf2f(v[j]);
  }
  float rle = 1.f / l;
  bf8 o;
#pragma unroll
  for (int j = 0; j < 8; ++j) o[j] = f2bf(acc[j] * rle);
  int bb = row >> 13, h = (row >> 10) & 7, qr = row & 1023;
  *(bf8*)&cat[(size_t)(bb * 1024 + qr) * 1536 + 512 + h * 64 + d8] = o;
}

// ---------------------------------------------------------------- GEMM (outproj, dbuf, bf16 W^T)
// C[2048,512] = cat[2048,1536] @ W + bias ; tile 64x64; XCD-swizzled 1-D grid of 256
__global__ __launch_bounds__(256) void gemmo_k(
    const short* __restrict__ A, const short* __restrict__ wT,
    const float* __restrict__ bias, float* __restrict__ out)
{
  __shared__ __align__(16) short a_lds[2][64 * 40];
  __shared__ __align__(16) short b_lds[2][64 * 40];
  const int tid = threadIdx.x;
  const int w = tid >> 6, lane = tid & 63, g = lane >> 4, lr = lane & 15;
  const int id = blockIdx.x;
  const int m = ((id >> 3) & 3) | ((id & 7) << 2);
  const int n = id >> 5;
  const int m0 = m * 64, n0 = n * 64;
  const int K = 1536;

  f32x4 z = {0.f, 0.f, 0.f, 0.f};
  f32x4 acc[4];
#pragma unroll
  for (int mi = 0; mi < 4; ++mi) acc[mi] = z;

  const int arow = tid >> 2, ac8 = tid & 3;
  const int bcol = tid & 63, bj4 = tid >> 6;
  bf8 ra, rna, rb, rnb;

  auto LOADAB = [&](int kg, bf8& ab, bf8& bb) {
    ab = *(const bf8*)&A[(size_t)(m0 + arow) * K + kg + ac8 * 8];
    bb = *(const bf8*)&wT[(size_t)(n0 + bcol) * K + kg + bj4 * 8];
  };
  auto STAGE = [&](int b, bf8 ab, bf8 bb) {
    *(bf8*)&a_lds[b][arow * 40 + ((ac8 ^ (arow & 3)) << 3)] = ab;
    *(bf8*)&b_lds[b][bcol * 40 + ((bj4 ^ (bcol & 3)) << 3)] = bb;
  };

  const int nit = K >> 5;
  LOADAB(0, ra, rb);
  STAGE(0, ra, rb);
  LOADAB(32, rna, rnb);
  __syncthreads();

  for (int it = 0; it < nit; ++it) {
    if (it + 1 < nit) STAGE((it + 1) & 1, rna, rnb);
    if (it + 2 < nit) LOADAB((it + 2) * 32, rna, rnb);

    const int b = it & 1;
    bf8 afr[4], bfr;
#pragma unroll
    for (int mi = 0; mi < 4; ++mi) {
      int row = mi * 16 + lr;
      afr[mi] = *(const bf8*)&a_lds[b][row * 40 + ((g ^ (row & 3)) << 3)];
    }
    {
      int col = w * 16 + lr;
      bfr = *(const bf8*)&b_lds[b][col * 40 + ((g ^ (col & 3)) << 3)];
    }
#pragma unroll
    for (int mi = 0; mi < 4; ++mi) acc[mi] = mfma16(afr[mi], bfr, acc[mi]);
    __syncthreads();
  }

  {
    int col = n0 + w * 16 + lr;
    float bv = bias[col];
#pragma unroll
    for (int mi = 0; mi < 4; ++mi) {
      int rowb = m0 + mi * 16 + g * 4;
#pragma unroll
      for (int r = 0; r < 4; ++r)
        out[(size_t)(rowb + r) * 512 + col] = acc[mi][r] + bv;
    }
  }
}

// ---------------------------------------------------------------- launch
extern "C" void kernel_launch(void* const* d_in, const int* in_sizes, int n_in,
                              void* d_out, int out_size, void* d_ws, size_t ws_size,
                              hipStream_t stream) {
  const float* x     = (const float*)d_in[0];
  const float* fore  = (const float*)d_in[1];
  const float* post  = (const float*)d_in[2];
  const float* wq    = (const float*)d_in[3];
  const float* bq    = (const float*)d_in[4];
  const float* wkv1  = (const float*)d_in[5];
  const float* bkv1  = (const float*)d_in[6];
  const float* wkv2  = (const float*)d_in[7];
  const float* bkv2  = (const float*)d_in[8];
  const float* wproj = (const float*)d_in[9];
  const float* bproj = (const float*)d_in[10];

  char* ws = (char*)d_ws;
  short* qb  = (short*)ws;                          // 2048*512  bf16 =  2 MB
  short* kv1 = (short*)(ws + (2ull << 20));         // 8192*1024 bf16 = 16 MB
  short* kv2 = (short*)(ws + (18ull << 20));        // 512*1024  bf16 =  1 MB
  short* cat = (short*)(ws + (19ull << 20));        // 2048*1536 bf16 =  6 MB
  short* o1  = (short*)(ws + (25ull << 20));        // 8*16384*64 bf16 = 16 MB
  float* l1  = (float*)(ws + (41ull << 20));        // 8*16384 f32 = 512 KB
  short* wT  = (short*)(ws + (42ull << 20));        // 512*1536 bf16 = 1.5 MB

  mega1_k<<<1408, 256, 0, stream>>>(x, fore, post, wq, bq, wkv1, bkv1,
                                    wkv2, bkv2, wproj, qb, kv1, kv2, cat, wT);
  attn_k<<<1152, 256, 0, stream>>>(qb, kv1, kv2, o1, l1, cat);
  comb_k<<<512, 256, 0, stream>>>(o1, l1, cat);
  gemmo_k<<<256, 256, 0, stream>>>(cat, wT, bproj, (float*)d_out);
}